// Round 14
// baseline (227.751 us; speedup 1.0000x reference)
//
#include <hip/hip_runtime.h>
#include <hip/hip_bf16.h>
#include <math.h>

#define B_   64
#define L_   500
#define F_   256
#define H_   4
#define DK   64

typedef unsigned short u16;
typedef unsigned int   u32;
typedef __attribute__((ext_vector_type(8))) short short8;
typedef __attribute__((ext_vector_type(4))) float f32x4;

static __device__ __forceinline__ u16 f2bf(float f) {
    u32 u = __float_as_uint(f);
    u32 r = (u + 0x7FFFu + ((u >> 16) & 1u)) >> 16;
    return (u16)r;
}
// packed bf16 pair via HW v_cvt_pk_bf16_f32 (HIP intrinsic, RNE).
static __device__ __forceinline__ u32 pk2(float a, float b) {
    __hip_bfloat162 h = __float22bfloat162_rn(make_float2(a, b));
    u32 r; __builtin_memcpy(&r, &h, sizeof(r));
    return r;
}

// T2 group-swizzle for DMA-staged W matrices (256-wide K): within each
// 64-col K-chunk of row n, 16B-group g is stored at slot g^(n&7).
static __device__ __forceinline__ int swzW(int n, int k) {
    return n * 256 + (k & 192) + ((((k >> 3) & 7) ^ (n & 7)) << 3) + (k & 7);
}

#define GLDS16(g, l)                                                          \
    __builtin_amdgcn_global_load_lds(                                         \
        (const __attribute__((address_space(1))) void*)(g),                   \
        (__attribute__((address_space(3))) void*)(l), 16, 0, 0)

// ---------------------------------------------------------------------------
// Prep: bf16 transposed weights.
//  wqT/wvT/fcwT [256][256] ([n][k]) in swzW layout (proj/final DMA);
//  w1T[64][64] linear; w2T[512][64] group-swizzled (attn w2-DMA).
//  vhT group-swizzled [bh][4][64][128]: elem(d,l) -> chunk l>>7, row d,
//  slot ((l&127)>>3)^(d&15), byte (l&7). Zero-fills l in [500,512).
// ---------------------------------------------------------------------------
__global__ __launch_bounds__(256) void prep_kernel(
    const float* __restrict__ wq, const float* __restrict__ wv,
    const float* __restrict__ fcw, const float* __restrict__ w1,
    const float* __restrict__ w2,
    u16* __restrict__ wqT, u16* __restrict__ wvT, u16* __restrict__ fcwT,
    u16* __restrict__ w1T, u16* __restrict__ w2T, u16* __restrict__ vhT)
{
    int t = blockIdx.x * 256 + threadIdx.x;
    int stride = gridDim.x * 256;
    for (int i = t; i < 256 * 256; i += stride) {
        int n = i >> 8, k = i & 255;
        int d = swzW(n, k);
        wqT[d]  = f2bf(wq[k * 256 + n]);
        wvT[d]  = f2bf(wv[k * 256 + n]);
        fcwT[d] = f2bf(fcw[k * 256 + n]);
    }
    for (int i = t; i < 64 * 64; i += stride) {
        int n = i >> 6, k = i & 63;
        w1T[i] = f2bf(w1[k * 64 + n]);
    }
    for (int i = t; i < 512 * 64; i += stride) {
        int n = i >> 6, k = i & 63;
        int s = ((k >> 3) ^ (n & 7));
        w2T[(n << 6) + (s << 3) + (k & 7)] = f2bf(n < 500 ? w2[k * 500 + n] : 0.f);
    }
    // zero vhT padding l in [500,512) for every (bh, d), swizzled slots
    for (int i = t; i < 256 * 64 * 12; i += stride) {
        int l  = 500 + (i % 12);
        int d  = (i / 12) & 63;
        int bh = i / (12 * 64);
        int kl = l & 127;                       // chunk 3
        int slot = (kl >> 3) ^ (d & 15);
        vhT[(size_t)bh * 32768 + 3 * 8192 + d * 128 + slot * 8 + (kl & 7)] = 0;
    }
}

// ---------------------------------------------------------------------------
// Kernel 1: head projections, bf16 MFMA, b-aligned blocks (r12 form).
// W staged via global_load_lds DMA. X reg-staged into padded Xs.
// grid (512, 2); which=0: qh_bf [bh][500][64]; which=1: vhT swizzled.
// ---------------------------------------------------------------------------
__global__ __launch_bounds__(512) void proj_kernel(
    const float* __restrict__ q, const float* __restrict__ v,
    const u16* __restrict__ wqT, const u16* __restrict__ wvT,
    u16* __restrict__ qh_bf, u16* __restrict__ vhT)
{
    const int which = blockIdx.y;
    const float* __restrict__ x = which ? v : q;
    const u16*   __restrict__ wT = which ? wvT : wqT;

    __shared__ u16 Xs[64][72];                 // [m][k], padded (reg-staged)
    __shared__ __align__(16) u16 Ws[16384];    // [256][64] linear (DMA dest)

    const int tid  = threadIdx.x;
    const int wvid = tid >> 6, ln = tid & 63;
    const int n16  = ln & 15, quad = ln >> 4;
    const int wr   = wvid >> 2, wc = wvid & 3;   // 2 x 4
    const int b    = blockIdx.x >> 3;            // batch
    const int l0b  = (blockIdx.x & 7) * 64;      // 64-aligned row base within b

    f32x4 acc[2][4];
    #pragma unroll
    for (int mt = 0; mt < 2; mt++)
        #pragma unroll
        for (int nt = 0; nt < 4; nt++) acc[mt][nt] = (f32x4){0.f, 0.f, 0.f, 0.f};

    for (int kc = 0; kc < 256; kc += 64) {
        // issue W DMA first (lands under X staging)
        #pragma unroll
        for (int j = 0; j < 4; j++) {
            int idx = tid + 512 * j;
            GLDS16(wT + (idx >> 3) * 256 + kc + (idx & 7) * 8, &Ws[idx * 8]);
        }
        // stage X (fp32 -> bf16 via packed cvt): 64 x 64, l>=500 -> 0
        #pragma unroll
        for (int j = 0; j < 2; j++) {
            int idx = tid + 512 * j;
            int m = idx >> 4, k4 = idx & 15;
            int l = l0b + m;
            float4 a = (float4){0.f, 0.f, 0.f, 0.f};
            if (l < 500)
                a = *(const float4*)&x[(size_t)(b * 500 + l) * 256 + kc + k4 * 4];
            uint2 uu = { pk2(a.x, a.y), pk2(a.z, a.w) };
            *(uint2*)&Xs[m][k4 * 4] = uu;
        }
        __syncthreads();    // drains DMA (vmcnt) + X writes (lgkm)
        #pragma unroll
        for (int ks = 0; ks < 2; ks++) {
            short8 af[2], bfr[4];
            #pragma unroll
            for (int mt = 0; mt < 2; mt++)
                af[mt] = *(const short8*)&Xs[wr * 32 + mt * 16 + n16][ks * 32 + quad * 8];
            #pragma unroll
            for (int nt = 0; nt < 4; nt++) {
                int n = wc * 64 + nt * 16 + n16;
                int s = (ks * 4 + quad) ^ (n16 & 7);
                bfr[nt] = *(const short8*)&Ws[n * 64 + s * 8];
            }
            #pragma unroll
            for (int mt = 0; mt < 2; mt++)
                #pragma unroll
                for (int nt = 0; nt < 4; nt++)
                    acc[mt][nt] = __builtin_amdgcn_mfma_f32_16x16x32_bf16(
                        af[mt], bfr[nt], acc[mt][nt], 0, 0, 0);
        }
        __syncthreads();
    }

    if (which == 0) {
        #pragma unroll
        for (int mt = 0; mt < 2; mt++) {
            int lrow = l0b + wr * 32 + mt * 16 + quad * 4;
            if (lrow < 500) {
                #pragma unroll
                for (int nt = 0; nt < 4; nt++) {
                    int d = nt * 16 + n16;
                    u16* dst = qh_bf + ((size_t)((b * 4 + wc) * 500 + lrow)) * 64 + d;
                    u32 p01 = pk2(acc[mt][nt][0], acc[mt][nt][1]);
                    u32 p23 = pk2(acc[mt][nt][2], acc[mt][nt][3]);
                    dst[0]   = (u16)p01;
                    dst[64]  = (u16)(p01 >> 16);
                    dst[128] = (u16)p23;
                    dst[192] = (u16)(p23 >> 16);
                }
            }
        }
    } else {
        #pragma unroll
        for (int mt = 0; mt < 2; mt++) {
            int lrow = l0b + wr * 32 + mt * 16 + quad * 4;
            if (lrow < 500) {
                int cc = lrow >> 7, kl = lrow & 127;
                #pragma unroll
                for (int nt = 0; nt < 4; nt++) {
                    int d = nt * 16 + n16;
                    int slot = (kl >> 3) ^ n16;           // d&15 == n16
                    uint2 uu = { pk2(acc[mt][nt][0], acc[mt][nt][1]),
                                 pk2(acc[mt][nt][2], acc[mt][nt][3]) };
                    *(uint2*)&vhT[(size_t)((b * 4 + wc)) * 32768 + cc * 8192 +
                                  d * 128 + slot * 8 + (kl & 7)] = uu;
                }
            }
        }
    }
}

// ---------------------------------------------------------------------------
// Kernel 2: dense-synthesizer attention (r13 schedule; w2 AND V via DMA).
// V buffers are LINEAR [64][128] (16 KB at 0 / 16384), filled by
// global_load_lds from the pre-swizzled vhT; PV reads XOR the slot
// ((ks*4+quad)^n16 -> 2-way banks = free). V0's DMA is issued during
// Phase B chunk 3 (w2lin0 dead after chunk 2's barrier; region disjoint
// from chunk 3's w2lin1 reads) -> the V0-publish barrier disappears.
// Region audit: vbufA 0..16383 (= w2lin0), vbufB 16384..32767 (overlaps
// w2lin1 20480.. only after Phase B fully done). Barriers: 8 (r13: 9).
// ---------------------------------------------------------------------------
__global__ __launch_bounds__(256) void attn_kernel(
    const u16* __restrict__ qh, const u16* __restrict__ vhT,
    const u16* __restrict__ w1T, const float* __restrict__ b1,
    const u16* __restrict__ w2T, const float* __restrict__ b2,
    u16* __restrict__ ctx)
{
    __shared__ __align__(16) char lds_raw[36864];   // w2 lin dbuf | V lin dbuf
    __shared__ __align__(16) u16 pls[4][16][136];   // per-wave s/P tile
    u16* w2lin0 = (u16*) lds_raw;                        // 0..16383
    u16* w2lin1 = (u16*)(lds_raw + 20480);               // 20480..36863
    u16* vbufA  = (u16*) lds_raw;                        // 0..16383
    u16* vbufB  = (u16*)(lds_raw + 16384);               // 16384..32767

    const int tid  = threadIdx.x;
    const int wv   = tid >> 6;
    const int ln   = tid & 63;
    const int n16  = ln & 15;
    const int quad = ln >> 4;
    const int bh   = blockIdx.x;
    const int r0   = blockIdx.y * 64 + wv * 16;

    const u16* __restrict__ vgbase = vhT + (size_t)bh * 32768;
    u16 (*pw)[136] = pls[wv];

    // ---- issue w2 chunk-0 DMA (lands during Phase A) ----
    #pragma unroll
    for (int j = 0; j < 4; j++) {
        int idx = tid + 256 * j;
        GLDS16(w2T + idx * 8, w2lin0 + idx * 8);
    }

    // ---- Phase A: s = relu(qh @ w1 + b1) -> private LDS -> A-frags ----
    short8 sa0, sa1;
    {
        const u16* qbase = qh + ((size_t)(bh * 500 + r0 + n16)) * 64;
        short8 a0 = *(const short8*)(qbase + quad * 8);
        short8 a1 = *(const short8*)(qbase + 32 + quad * 8);
        #pragma unroll
        for (int nt = 0; nt < 4; nt++) {
            const u16* wb = w1T + (nt * 16 + n16) * 64;
            short8 bb0 = *(const short8*)(wb + quad * 8);
            short8 bb1 = *(const short8*)(wb + 32 + quad * 8);
            f32x4 c4 = {0.f, 0.f, 0.f, 0.f};
            c4 = __builtin_amdgcn_mfma_f32_16x16x32_bf16(a0, bb0, c4, 0, 0, 0);
            c4 = __builtin_amdgcn_mfma_f32_16x16x32_bf16(a1, bb1, c4, 0, 0, 0);
            float bias = b1[nt * 16 + n16];
            int col = nt * 16 + n16;
            u32 p01 = pk2(fmaxf(c4[0] + bias, 0.f), fmaxf(c4[1] + bias, 0.f));
            u32 p23 = pk2(fmaxf(c4[2] + bias, 0.f), fmaxf(c4[3] + bias, 0.f));
            pw[quad * 4 + 0][col] = (u16)p01;
            pw[quad * 4 + 1][col] = (u16)(p01 >> 16);
            pw[quad * 4 + 2][col] = (u16)p23;
            pw[quad * 4 + 3][col] = (u16)(p23 >> 16);
        }
        sa0 = *(const short8*)&pw[n16][quad * 8];
        sa1 = *(const short8*)&pw[n16][32 + quad * 8];
    }
    __syncthreads();                                     // sync 1: w2 chunk 0 ready

    // ---- Phase B: logits = s @ w2 + b2, DMA double-buffered ----
    f32x4 acc[32];
    for (int cc = 0; cc < 4; cc++) {
        if (cc < 3) {
            const u16* src = w2T + (cc + 1) * 8192;
            u16* dstl = ((cc + 1) & 1) ? w2lin1 : w2lin0;
            #pragma unroll
            for (int j = 0; j < 4; j++) {
                int idx = tid + 256 * j;
                GLDS16(src + idx * 8, dstl + idx * 8);
            }
        } else {
            // V0 DMA into vbufA: w2lin0 dead since chunk 2's barrier;
            // chunk 3 reads only w2lin1 (disjoint region).
            #pragma unroll
            for (int j = 0; j < 4; j++) {
                int idx = tid + 256 * j;
                GLDS16(vgbase + idx * 8, vbufA + idx * 8);
            }
        }
        const u16* buf = (cc & 1) ? w2lin1 : w2lin0;
        #pragma unroll
        for (int t = 0; t < 8; t++) {
            int nt = cc * 8 + t;
            int n  = t * 16 + n16;
            int s0 = quad ^ (n16 & 7);
            int s1 = (quad + 4) ^ (n16 & 7);
            short8 bb0 = *(const short8*)&buf[n * 64 + s0 * 8];
            short8 bb1 = *(const short8*)&buf[n * 64 + s1 * 8];
            f32x4 c = {0.f, 0.f, 0.f, 0.f};
            c = __builtin_amdgcn_mfma_f32_16x16x32_bf16(sa0, bb0, c, 0, 0, 0);
            c = __builtin_amdgcn_mfma_f32_16x16x32_bf16(sa1, bb1, c, 0, 0, 0);
            int col = cc * 128 + t * 16 + n16;
            float bias = (col < 500) ? b2[col] : -INFINITY;
            #pragma unroll
            for (int i = 0; i < 4; i++) c[i] += bias;
            acc[nt] = c;
        }
        __syncthreads();                                 // sync 2-5
    }
    // sync 5 drained the V0 DMA -> vbufA ready; softmax is barrier-free.

    // ---- softmax stats (P unnormalized; fold 1/sum into epilogue) ----
    float inv[4];
    {
        float mx[4], sm[4];
        #pragma unroll
        for (int i = 0; i < 4; i++) mx[i] = acc[0][i];
        #pragma unroll
        for (int nt = 1; nt < 32; nt++)
            #pragma unroll
            for (int i = 0; i < 4; i++) mx[i] = fmaxf(mx[i], acc[nt][i]);
        #pragma unroll
        for (int off = 1; off < 16; off <<= 1)
            #pragma unroll
            for (int i = 0; i < 4; i++) mx[i] = fmaxf(mx[i], __shfl_xor(mx[i], off));
        #pragma unroll
        for (int i = 0; i < 4; i++) sm[i] = 0.f;
        #pragma unroll
        for (int nt = 0; nt < 32; nt++)
            #pragma unroll
            for (int i = 0; i < 4; i++) {
                float e = __expf(acc[nt][i] - mx[i]);
                acc[nt][i] = e;
                sm[i] += e;
            }
        #pragma unroll
        for (int off = 1; off < 16; off <<= 1)
            #pragma unroll
            for (int i = 0; i < 4; i++) sm[i] += __shfl_xor(sm[i], off);
        #pragma unroll
        for (int i = 0; i < 4; i++) inv[i] = 1.f / sm[i];
    }

    // ---- Phase C: out = P @ vh, V DMA double-buffered ----
    f32x4 oacc[4];
    #pragma unroll
    for (int nt = 0; nt < 4; nt++) oacc[nt] = (f32x4){0.f, 0.f, 0.f, 0.f};

    for (int cc = 0; cc < 4; cc++) {
        const u16* vb = (cc & 1) ? vbufB : vbufA;
        u16*       vn = (cc & 1) ? vbufA : vbufB;

        // issue V(cc+1) DMA into the other buffer (WAR drained by the
        // barrier that ended chunk cc-1; next barrier drains this DMA)
        if (cc < 3) {
            const u16* src = vgbase + (cc + 1) * 8192;
            #pragma unroll
            for (int j = 0; j < 4; j++) {
                int idx = tid + 256 * j;
                GLDS16(src + idx * 8, vn + idx * 8);
            }
        }
        // P for this chunk (per-wave private, no barrier), packed converts
        #pragma unroll
        for (int t = 0; t < 8; t++) {
            int nt = cc * 8 + t;
            int c  = t * 16 + n16;
            u32 p01 = pk2(acc[nt][0], acc[nt][1]);
            u32 p23 = pk2(acc[nt][2], acc[nt][3]);
            pw[quad * 4 + 0][c] = (u16)p01;
            pw[quad * 4 + 1][c] = (u16)(p01 >> 16);
            pw[quad * 4 + 2][c] = (u16)p23;
            pw[quad * 4 + 3][c] = (u16)(p23 >> 16);
        }
        // PV MFMAs (swizzled V reads: slot = (ks*4+quad)^n16)
        #pragma unroll
        for (int ks = 0; ks < 4; ks++) {
            short8 pa = *(const short8*)&pw[n16][ks * 32 + quad * 8];
            int slot = (ks * 4 + quad) ^ n16;
            #pragma unroll
            for (int nt = 0; nt < 4; nt++) {
                short8 vvf = *(const short8*)&vb[(nt * 16 + n16) * 128 + slot * 8];
                oacc[nt] = __builtin_amdgcn_mfma_f32_16x16x32_bf16(pa, vvf, oacc[nt], 0, 0, 0);
            }
        }
        if (cc < 3) __syncthreads();                     // sync 6-8
    }

    // ---- epilogue: scale, write ctx bf16 (packed converts) ----
    {
        const int b = bh >> 2, h = bh & 3;
        #pragma unroll
        for (int i = 0; i < 4; i++) {
            int lrow = r0 + quad * 4 + i;
            if (lrow < 500) {
                float s = inv[i];
                u16* dst = &ctx[((size_t)(b * 500 + lrow)) * 256 + h * 64];
                u32 a01 = pk2(oacc[0][i] * s, oacc[1][i] * s);
                u32 a23 = pk2(oacc[2][i] * s, oacc[3][i] * s);
                dst[0 * 16 + n16] = (u16)a01;
                dst[1 * 16 + n16] = (u16)(a01 >> 16);
                dst[2 * 16 + n16] = (u16)a23;
                dst[3 * 16 + n16] = (u16)(a23 >> 16);
            }
        }
    }
}

// ---------------------------------------------------------------------------
// Kernel 3: out = LayerNorm(ctx @ fc_w + q) (r12 form: W via DMA).
// grid (500), block 512 = 8 waves in 2x4; block tile 64 rows x 256 cols.
// ---------------------------------------------------------------------------
__global__ __launch_bounds__(512) void final_kernel(
    const u16* __restrict__ ctx, const u16* __restrict__ fcwT,
    const float* __restrict__ qres, const float* __restrict__ g,
    const float* __restrict__ bta, float* __restrict__ out)
{
    __shared__ u16 Xs[64][72];
    __shared__ __align__(16) u16 Ws[16384];    // [256][64] linear (DMA dest)
    __shared__ float red[4][2][64];   // [wc][s1|s2][row]
    __shared__ float murs[2][64];     // [mu|rs][row]

    const int tid  = threadIdx.x;
    const int wvid = tid >> 6, ln = tid & 63;
    const int n16  = ln & 15, quad = ln >> 4;
    const int wr   = wvid >> 2, wc = wvid & 3;   // 2 x 4
    const int row0 = blockIdx.x * 64;

    f32x4 acc[2][4];
    #pragma unroll
    for (int mt = 0; mt < 2; mt++)
        #pragma unroll
        for (int nt = 0; nt < 4; nt++) acc[mt][nt] = (f32x4){0.f, 0.f, 0.f, 0.f};

    for (int kc = 0; kc < 256; kc += 64) {
        // issue W DMA first
        #pragma unroll
        for (int j = 0; j < 4; j++) {
            int idx = tid + 512 * j;
            GLDS16(fcwT + (idx >> 3) * 256 + kc + (idx & 7) * 8, &Ws[idx * 8]);
        }
        // stage X: 64 x 64 bf16
        {
            int m = tid >> 3, k8 = tid & 7;
            *(uint4*)&Xs[m][k8 * 8] =
                *(const uint4*)&ctx[(size_t)(row0 + m) * 256 + kc + k8 * 8];
        }
        __syncthreads();
        #pragma unroll
        for (int ks = 0; ks < 2; ks++) {
            short8 af[2], bfr[4];
            #pragma unroll
            for (int mt = 0; mt < 2; mt++)
                af[mt] = *(const short8*)&Xs[wr * 32 + mt * 16 + n16][ks * 32 + quad * 8];
            #pragma unroll
            for (int nt = 0; nt < 4; nt++) {
                int n = wc * 64 + nt * 16 + n16;
                int s = (ks * 4 + quad) ^ (n16 & 7);
                bfr[nt] = *(const short8*)&Ws[n * 64 + s * 8];
            }
            #pragma unroll
            for (int mt = 0; mt < 2; mt++)
                #pragma unroll
                for (int nt = 0; nt < 4; nt++)
                    acc[mt][nt] = __builtin_amdgcn_mfma_f32_16x16x32_bf16(
                        af[mt], bfr[nt], acc[mt][nt], 0, 0, 0);
        }
        __syncthreads();
    }

    // residual add
    #pragma unroll
    for (int mt = 0; mt < 2; mt++) {
        int m0 = row0 + wr * 32 + mt * 16 + quad * 4;
        #pragma unroll
        for (int i = 0; i < 4; i++) {
            const float* rp = &qres[(size_t)(m0 + i) * 256 + wc * 64 + n16];
            #pragma unroll
            for (int nt = 0; nt < 4; nt++)
                acc[mt][nt][i] += rp[nt * 16];
        }
    }
    // per-row partial sums -> LDS
    #pragma unroll
    for (int mt = 0; mt < 2; mt++) {
        #pragma unroll
        for (int i = 0; i < 4; i++) {
            float s1 = 0.f, s2 = 0.f;
            #pragma unroll
            for (int nt = 0; nt < 4; nt++) {
                float vv = acc[mt][nt][i];
                s1 += vv; s2 += vv * vv;
            }
            #pragma unroll
            for (int off = 1; off < 16; off <<= 1) {
                s1 += __shfl_xor(s1, off);
                s2 += __shfl_xor(s2, off);
            }
            if (n16 == 0) {
                int r = wr * 32 + mt * 16 + quad * 4 + i;
                red[wc][0][r] = s1;
                red[wc][1][r] = s2;
            }
        }
    }
    __syncthreads();
    if (tid < 64) {
        float S1 = red[0][0][tid] + red[1][0][tid] + red[2][0][tid] + red[3][0][tid];
        float S2 = red[0][1][tid] + red[1][1][tid] + red[2][1][tid] + red[3][1][tid];
        float mu  = S1 * 0.00390625f;
        float var = S2 * 0.00390625f - mu * mu;
        murs[0][tid] = mu;
        murs[1][tid] = rsqrtf(var + 1e-6f);
    }
    __syncthreads();

    float gv[4], bv[4];
    #pragma unroll
    for (int nt = 0; nt < 4; nt++) {
        int col = wc * 64 + nt * 16 + n16;
        gv[nt] = g[col];
        bv[nt] = bta[col];
    }
    #pragma unroll
    for (int mt = 0; mt < 2; mt++) {
        int rb = wr * 32 + mt * 16 + quad * 4;
        #pragma unroll
        for (int i = 0; i < 4; i++) {
            float mu = murs[0][rb + i];
            float rs = murs[1][rb + i];
            float* op = &out[(size_t)(row0 + rb + i) * 256 + wc * 64 + n16];
            #pragma unroll
            for (int nt = 0; nt < 4; nt++)
                op[nt * 16] = (acc[mt][nt][i] - mu) * rs * gv[nt] + bv[nt];
        }
    }
}

// ---------------------------------------------------------------------------
extern "C" void kernel_launch(void* const* d_in, const int* in_sizes, int n_in,
                              void* d_out, int out_size, void* d_ws, size_t ws_size,
                              hipStream_t stream)
{
    const float* q   = (const float*)d_in[0];
    const float* v   = (const float*)d_in[2];
    const float* wqs = (const float*)d_in[3];
    const float* wvs = (const float*)d_in[4];
    const float* w1  = (const float*)d_in[5];
    const float* b1  = (const float*)d_in[6];
    const float* w2  = (const float*)d_in[7];
    const float* b2  = (const float*)d_in[8];
    const float* fcw = (const float*)d_in[9];
    const float* lng = (const float*)d_in[10];
    const float* lnb = (const float*)d_in[11];
    float* out = (float*)d_out;

    u16* qh_bf = (u16*)d_ws;            // 8,200,192 (padded: attn reads rows <512)
    u16* vhT   = qh_bf + 8200192;       // 8,388,608  (swizzled [bh][4][64][128])
    u16* w1T   = vhT + 8388608;         // 4,096
    u16* w2T   = w1T + 4096;            // 32,768     (group-swizzled [512][64])
    u16* wqT   = w2T + 32768;           // 65,536     (swzW layout)
    u16* wvT   = wqT + 65536;           // 65,536     (swzW layout)
    u16* fcwT  = wvT + 65536;           // 65,536     (swzW layout)
    u16* ctx   = fcwT + 65536;          // 8,192,000

    prep_kernel <<<dim3(256),    256, 0, stream>>>(wqs, wvs, fcw, w1, w2,
                                                   wqT, wvT, fcwT, w1T, w2T, vhT);
    proj_kernel <<<dim3(512, 2), 512, 0, stream>>>(q, v, wqT, wvT, qh_bf, vhT);
    attn_kernel <<<dim3(256, 8), 256, 0, stream>>>(qh_bf, vhT, w1T, b1, w2T, b2, ctx);
    final_kernel<<<dim3(500),    512, 0, stream>>>(ctx, fcwT, q, lng, lnb, out);
}

// Round 16
// 225.815 us; speedup vs baseline: 1.0086x; 1.0086x over previous
//
#include <hip/hip_runtime.h>
#include <hip/hip_bf16.h>
#include <math.h>

#define B_   64
#define L_   500
#define F_   256
#define H_   4
#define DK   64

typedef unsigned short u16;
typedef unsigned int   u32;
typedef __attribute__((ext_vector_type(8))) short short8;
typedef __attribute__((ext_vector_type(4))) float f32x4;

static __device__ __forceinline__ u16 f2bf(float f) {
    u32 u = __float_as_uint(f);
    u32 r = (u + 0x7FFFu + ((u >> 16) & 1u)) >> 16;
    return (u16)r;
}
// packed bf16 pair via HW v_cvt_pk_bf16_f32 (HIP intrinsic, RNE).
static __device__ __forceinline__ u32 pk2(float a, float b) {
    __hip_bfloat162 h = __float22bfloat162_rn(make_float2(a, b));
    u32 r; __builtin_memcpy(&r, &h, sizeof(r));
    return r;
}

// T2 group-swizzle for DMA-staged W matrices (256-wide K): within each
// 64-col K-chunk of row n, 16B-group g is stored at slot g^(n&7).
static __device__ __forceinline__ int swzW(int n, int k) {
    return n * 256 + (k & 192) + ((((k >> 3) & 7) ^ (n & 7)) << 3) + (k & 7);
}

#define GLDS16(g, l)                                                          \
    __builtin_amdgcn_global_load_lds(                                         \
        (const __attribute__((address_space(1))) void*)(g),                   \
        (__attribute__((address_space(3))) void*)(l), 16, 0, 0)

// ---------------------------------------------------------------------------
// Prep: bf16 transposed weights.
//  wqT/wvT/fcwT [256][256] ([n][k]) in swzW layout (proj/final DMA);
//  w1T[64][64] linear; w2T[512][64] group-swizzled (attn w2-DMA).
//  vhT group-swizzled [bh][4][64][128]: elem(d,l) -> chunk l>>7, row d,
//  slot ((l&127)>>3)^(d&15), byte (l&7). Zero-fills l in [500,512).
// ---------------------------------------------------------------------------
__global__ __launch_bounds__(256) void prep_kernel(
    const float* __restrict__ wq, const float* __restrict__ wv,
    const float* __restrict__ fcw, const float* __restrict__ w1,
    const float* __restrict__ w2,
    u16* __restrict__ wqT, u16* __restrict__ wvT, u16* __restrict__ fcwT,
    u16* __restrict__ w1T, u16* __restrict__ w2T, u16* __restrict__ vhT)
{
    int t = blockIdx.x * 256 + threadIdx.x;
    int stride = gridDim.x * 256;
    for (int i = t; i < 256 * 256; i += stride) {
        int n = i >> 8, k = i & 255;
        int d = swzW(n, k);
        wqT[d]  = f2bf(wq[k * 256 + n]);
        wvT[d]  = f2bf(wv[k * 256 + n]);
        fcwT[d] = f2bf(fcw[k * 256 + n]);
    }
    for (int i = t; i < 64 * 64; i += stride) {
        int n = i >> 6, k = i & 63;
        w1T[i] = f2bf(w1[k * 64 + n]);
    }
    for (int i = t; i < 512 * 64; i += stride) {
        int n = i >> 6, k = i & 63;
        int s = ((k >> 3) ^ (n & 7));
        w2T[(n << 6) + (s << 3) + (k & 7)] = f2bf(n < 500 ? w2[k * 500 + n] : 0.f);
    }
    // zero vhT padding l in [500,512) for every (bh, d), swizzled slots
    for (int i = t; i < 256 * 64 * 12; i += stride) {
        int l  = 500 + (i % 12);
        int d  = (i / 12) & 63;
        int bh = i / (12 * 64);
        int kl = l & 127;                       // chunk 3
        int slot = (kl >> 3) ^ (d & 15);
        vhT[(size_t)bh * 32768 + 3 * 8192 + d * 128 + slot * 8 + (kl & 7)] = 0;
    }
}

// ---------------------------------------------------------------------------
// Kernel 1: head projections, bf16 MFMA, b-aligned blocks (r12 form).
// W staged via global_load_lds DMA. X reg-staged into padded Xs.
// grid (512, 2); which=0: qh_bf [bh][500][64]; which=1: vhT swizzled.
// ---------------------------------------------------------------------------
__global__ __launch_bounds__(512) void proj_kernel(
    const float* __restrict__ q, const float* __restrict__ v,
    const u16* __restrict__ wqT, const u16* __restrict__ wvT,
    u16* __restrict__ qh_bf, u16* __restrict__ vhT)
{
    const int which = blockIdx.y;
    const float* __restrict__ x = which ? v : q;
    const u16*   __restrict__ wT = which ? wvT : wqT;

    __shared__ u16 Xs[64][72];                 // [m][k], padded (reg-staged)
    __shared__ __align__(16) u16 Ws[16384];    // [256][64] linear (DMA dest)

    const int tid  = threadIdx.x;
    const int wvid = tid >> 6, ln = tid & 63;
    const int n16  = ln & 15, quad = ln >> 4;
    const int wr   = wvid >> 2, wc = wvid & 3;   // 2 x 4
    const int b    = blockIdx.x >> 3;            // batch
    const int l0b  = (blockIdx.x & 7) * 64;      // 64-aligned row base within b

    f32x4 acc[2][4];
    #pragma unroll
    for (int mt = 0; mt < 2; mt++)
        #pragma unroll
        for (int nt = 0; nt < 4; nt++) acc[mt][nt] = (f32x4){0.f, 0.f, 0.f, 0.f};

    for (int kc = 0; kc < 256; kc += 64) {
        // issue W DMA first (lands under X staging)
        #pragma unroll
        for (int j = 0; j < 4; j++) {
            int idx = tid + 512 * j;
            GLDS16(wT + (idx >> 3) * 256 + kc + (idx & 7) * 8, &Ws[idx * 8]);
        }
        // stage X (fp32 -> bf16 via packed cvt): 64 x 64, l>=500 -> 0
        #pragma unroll
        for (int j = 0; j < 2; j++) {
            int idx = tid + 512 * j;
            int m = idx >> 4, k4 = idx & 15;
            int l = l0b + m;
            float4 a = (float4){0.f, 0.f, 0.f, 0.f};
            if (l < 500)
                a = *(const float4*)&x[(size_t)(b * 500 + l) * 256 + kc + k4 * 4];
            uint2 uu = { pk2(a.x, a.y), pk2(a.z, a.w) };
            *(uint2*)&Xs[m][k4 * 4] = uu;
        }
        __syncthreads();    // drains DMA (vmcnt) + X writes (lgkm)
        #pragma unroll
        for (int ks = 0; ks < 2; ks++) {
            short8 af[2], bfr[4];
            #pragma unroll
            for (int mt = 0; mt < 2; mt++)
                af[mt] = *(const short8*)&Xs[wr * 32 + mt * 16 + n16][ks * 32 + quad * 8];
            #pragma unroll
            for (int nt = 0; nt < 4; nt++) {
                int n = wc * 64 + nt * 16 + n16;
                int s = (ks * 4 + quad) ^ (n16 & 7);
                bfr[nt] = *(const short8*)&Ws[n * 64 + s * 8];
            }
            #pragma unroll
            for (int mt = 0; mt < 2; mt++)
                #pragma unroll
                for (int nt = 0; nt < 4; nt++)
                    acc[mt][nt] = __builtin_amdgcn_mfma_f32_16x16x32_bf16(
                        af[mt], bfr[nt], acc[mt][nt], 0, 0, 0);
        }
        __syncthreads();
    }

    if (which == 0) {
        #pragma unroll
        for (int mt = 0; mt < 2; mt++) {
            int lrow = l0b + wr * 32 + mt * 16 + quad * 4;
            if (lrow < 500) {
                #pragma unroll
                for (int nt = 0; nt < 4; nt++) {
                    int d = nt * 16 + n16;
                    u16* dst = qh_bf + ((size_t)((b * 4 + wc) * 500 + lrow)) * 64 + d;
                    u32 p01 = pk2(acc[mt][nt][0], acc[mt][nt][1]);
                    u32 p23 = pk2(acc[mt][nt][2], acc[mt][nt][3]);
                    dst[0]   = (u16)p01;
                    dst[64]  = (u16)(p01 >> 16);
                    dst[128] = (u16)p23;
                    dst[192] = (u16)(p23 >> 16);
                }
            }
        }
    } else {
        #pragma unroll
        for (int mt = 0; mt < 2; mt++) {
            int lrow = l0b + wr * 32 + mt * 16 + quad * 4;
            if (lrow < 500) {
                int cc = lrow >> 7, kl = lrow & 127;
                #pragma unroll
                for (int nt = 0; nt < 4; nt++) {
                    int d = nt * 16 + n16;
                    int slot = (kl >> 3) ^ n16;           // d&15 == n16
                    uint2 uu = { pk2(acc[mt][nt][0], acc[mt][nt][1]),
                                 pk2(acc[mt][nt][2], acc[mt][nt][3]) };
                    *(uint2*)&vhT[(size_t)((b * 4 + wc)) * 32768 + cc * 8192 +
                                  d * 128 + slot * 8 + (kl & 7)] = uu;
                }
            }
        }
    }
}

// ---------------------------------------------------------------------------
// Kernel 2: dense-synthesizer attention (r14 schedule; w2+V via DMA).
// (1) V1 DMA issued BEFORE softmax (w2lin1 dead after Phase B's last
// barrier; softmax VALU covers the DMA); Phase C issues V2/V3 at cc=1/2.
// (2) ctx written group-swizzled within each 64-col h-block (g ^= grow&7)
// so final can DMA its X tile. Barriers: 8.
// ---------------------------------------------------------------------------
__global__ __launch_bounds__(256) void attn_kernel(
    const u16* __restrict__ qh, const u16* __restrict__ vhT,
    const u16* __restrict__ w1T, const float* __restrict__ b1,
    const u16* __restrict__ w2T, const float* __restrict__ b2,
    u16* __restrict__ ctx)
{
    __shared__ __align__(16) char lds_raw[36864];   // w2 lin dbuf | V lin dbuf
    __shared__ __align__(16) u16 pls[4][16][136];   // per-wave s/P tile
    u16* w2lin0 = (u16*) lds_raw;                        // 0..16383
    u16* w2lin1 = (u16*)(lds_raw + 20480);               // 20480..36863
    u16* vbufA  = (u16*) lds_raw;                        // 0..16383
    u16* vbufB  = (u16*)(lds_raw + 16384);               // 16384..32767

    const int tid  = threadIdx.x;
    const int wv   = tid >> 6;
    const int ln   = tid & 63;
    const int n16  = ln & 15;
    const int quad = ln >> 4;
    const int bh   = blockIdx.x;
    const int r0   = blockIdx.y * 64 + wv * 16;

    const u16* __restrict__ vgbase = vhT + (size_t)bh * 32768;
    u16 (*pw)[136] = pls[wv];

    // ---- issue w2 chunk-0 DMA (lands during Phase A) ----
    #pragma unroll
    for (int j = 0; j < 4; j++) {
        int idx = tid + 256 * j;
        GLDS16(w2T + idx * 8, w2lin0 + idx * 8);
    }

    // ---- Phase A: s = relu(qh @ w1 + b1) -> private LDS -> A-frags ----
    short8 sa0, sa1;
    {
        const u16* qbase = qh + ((size_t)(bh * 500 + r0 + n16)) * 64;
        short8 a0 = *(const short8*)(qbase + quad * 8);
        short8 a1 = *(const short8*)(qbase + 32 + quad * 8);
        #pragma unroll
        for (int nt = 0; nt < 4; nt++) {
            const u16* wb = w1T + (nt * 16 + n16) * 64;
            short8 bb0 = *(const short8*)(wb + quad * 8);
            short8 bb1 = *(const short8*)(wb + 32 + quad * 8);
            f32x4 c4 = {0.f, 0.f, 0.f, 0.f};
            c4 = __builtin_amdgcn_mfma_f32_16x16x32_bf16(a0, bb0, c4, 0, 0, 0);
            c4 = __builtin_amdgcn_mfma_f32_16x16x32_bf16(a1, bb1, c4, 0, 0, 0);
            float bias = b1[nt * 16 + n16];
            int col = nt * 16 + n16;
            u32 p01 = pk2(fmaxf(c4[0] + bias, 0.f), fmaxf(c4[1] + bias, 0.f));
            u32 p23 = pk2(fmaxf(c4[2] + bias, 0.f), fmaxf(c4[3] + bias, 0.f));
            pw[quad * 4 + 0][col] = (u16)p01;
            pw[quad * 4 + 1][col] = (u16)(p01 >> 16);
            pw[quad * 4 + 2][col] = (u16)p23;
            pw[quad * 4 + 3][col] = (u16)(p23 >> 16);
        }
        sa0 = *(const short8*)&pw[n16][quad * 8];
        sa1 = *(const short8*)&pw[n16][32 + quad * 8];
    }
    __syncthreads();                                     // sync 1: w2 chunk 0 ready

    // ---- Phase B: logits = s @ w2 + b2, DMA double-buffered ----
    f32x4 acc[32];
    for (int cc = 0; cc < 4; cc++) {
        if (cc < 3) {
            const u16* src = w2T + (cc + 1) * 8192;
            u16* dstl = ((cc + 1) & 1) ? w2lin1 : w2lin0;
            #pragma unroll
            for (int j = 0; j < 4; j++) {
                int idx = tid + 256 * j;
                GLDS16(src + idx * 8, dstl + idx * 8);
            }
        } else {
            // V0 DMA into vbufA: w2lin0 dead since chunk 2's barrier;
            // chunk 3 reads only w2lin1 (disjoint region).
            #pragma unroll
            for (int j = 0; j < 4; j++) {
                int idx = tid + 256 * j;
                GLDS16(vgbase + idx * 8, vbufA + idx * 8);
            }
        }
        const u16* buf = (cc & 1) ? w2lin1 : w2lin0;
        #pragma unroll
        for (int t = 0; t < 8; t++) {
            int nt = cc * 8 + t;
            int n  = t * 16 + n16;
            int s0 = quad ^ (n16 & 7);
            int s1 = (quad + 4) ^ (n16 & 7);
            short8 bb0 = *(const short8*)&buf[n * 64 + s0 * 8];
            short8 bb1 = *(const short8*)&buf[n * 64 + s1 * 8];
            f32x4 c = {0.f, 0.f, 0.f, 0.f};
            c = __builtin_amdgcn_mfma_f32_16x16x32_bf16(sa0, bb0, c, 0, 0, 0);
            c = __builtin_amdgcn_mfma_f32_16x16x32_bf16(sa1, bb1, c, 0, 0, 0);
            int col = cc * 128 + t * 16 + n16;
            float bias = (col < 500) ? b2[col] : -INFINITY;
            #pragma unroll
            for (int i = 0; i < 4; i++) c[i] += bias;
            acc[nt] = c;
        }
        __syncthreads();                                 // sync 2-5
    }
    // sync 5 drained V0 -> vbufA ready.

    // ---- issue V1 DMA now (w2lin1 dead; softmax VALU covers it) ----
    {
        const u16* src = vgbase + 8192;
        #pragma unroll
        for (int j = 0; j < 4; j++) {
            int idx = tid + 256 * j;
            GLDS16(src + idx * 8, vbufB + idx * 8);
        }
    }

    // ---- softmax stats (P unnormalized; fold 1/sum into epilogue) ----
    float inv[4];
    {
        float mx[4], sm[4];
        #pragma unroll
        for (int i = 0; i < 4; i++) mx[i] = acc[0][i];
        #pragma unroll
        for (int nt = 1; nt < 32; nt++)
            #pragma unroll
            for (int i = 0; i < 4; i++) mx[i] = fmaxf(mx[i], acc[nt][i]);
        #pragma unroll
        for (int off = 1; off < 16; off <<= 1)
            #pragma unroll
            for (int i = 0; i < 4; i++) mx[i] = fmaxf(mx[i], __shfl_xor(mx[i], off));
        #pragma unroll
        for (int i = 0; i < 4; i++) sm[i] = 0.f;
        #pragma unroll
        for (int nt = 0; nt < 32; nt++)
            #pragma unroll
            for (int i = 0; i < 4; i++) {
                float e = __expf(acc[nt][i] - mx[i]);
                acc[nt][i] = e;
                sm[i] += e;
            }
        #pragma unroll
        for (int off = 1; off < 16; off <<= 1)
            #pragma unroll
            for (int i = 0; i < 4; i++) sm[i] += __shfl_xor(sm[i], off);
        #pragma unroll
        for (int i = 0; i < 4; i++) inv[i] = 1.f / sm[i];
    }

    // ---- Phase C: out = P @ vh, V DMA double-buffered ----
    f32x4 oacc[4];
    #pragma unroll
    for (int nt = 0; nt < 4; nt++) oacc[nt] = (f32x4){0.f, 0.f, 0.f, 0.f};

    for (int cc = 0; cc < 4; cc++) {
        const u16* vb = (cc & 1) ? vbufB : vbufA;
        u16*       vn = (cc & 1) ? vbufA : vbufB;

        // V2/V3 DMA into the buffer freed by the preceding barrier
        // (V1 was issued pre-softmax; barrier at end of cc drains it)
        if (cc >= 1 && cc < 3) {
            const u16* src = vgbase + (cc + 1) * 8192;
            #pragma unroll
            for (int j = 0; j < 4; j++) {
                int idx = tid + 256 * j;
                GLDS16(src + idx * 8, vn + idx * 8);
            }
        }
        // P for this chunk (per-wave private, no barrier), packed converts
        #pragma unroll
        for (int t = 0; t < 8; t++) {
            int nt = cc * 8 + t;
            int c  = t * 16 + n16;
            u32 p01 = pk2(acc[nt][0], acc[nt][1]);
            u32 p23 = pk2(acc[nt][2], acc[nt][3]);
            pw[quad * 4 + 0][c] = (u16)p01;
            pw[quad * 4 + 1][c] = (u16)(p01 >> 16);
            pw[quad * 4 + 2][c] = (u16)p23;
            pw[quad * 4 + 3][c] = (u16)(p23 >> 16);
        }
        // PV MFMAs (swizzled V reads: slot = (ks*4+quad)^n16)
        #pragma unroll
        for (int ks = 0; ks < 4; ks++) {
            short8 pa = *(const short8*)&pw[n16][ks * 32 + quad * 8];
            int slot = (ks * 4 + quad) ^ n16;
            #pragma unroll
            for (int nt = 0; nt < 4; nt++) {
                short8 vvf = *(const short8*)&vb[(nt * 16 + n16) * 128 + slot * 8];
                oacc[nt] = __builtin_amdgcn_mfma_f32_16x16x32_bf16(pa, vvf, oacc[nt], 0, 0, 0);
            }
        }
        if (cc < 3) __syncthreads();                     // sync 6-8
    }

    // ---- epilogue: scale, write ctx bf16, GROUP-SWIZZLED per h-block:
    // elem d of row grow stored at ((d>>3)^(grow&7))*8 + (d&7). ----
    {
        const int b = bh >> 2, h = bh & 3;
        const int g8 = n16 >> 3, d7 = n16 & 7;
        #pragma unroll
        for (int i = 0; i < 4; i++) {
            int lrow = r0 + quad * 4 + i;
            if (lrow < 500) {
                float s = inv[i];
                int grow = b * 500 + lrow;
                int key = grow & 7;
                u16* dst = &ctx[(size_t)grow * 256 + h * 64];
                u32 a01 = pk2(oacc[0][i] * s, oacc[1][i] * s);
                u32 a23 = pk2(oacc[2][i] * s, oacc[3][i] * s);
                dst[(((0 + g8) ^ key) << 3) + d7] = (u16)a01;
                dst[(((2 + g8) ^ key) << 3) + d7] = (u16)(a01 >> 16);
                dst[(((4 + g8) ^ key) << 3) + d7] = (u16)a23;
                dst[(((6 + g8) ^ key) << 3) + d7] = (u16)(a23 >> 16);
            }
        }
    }
}

// ---------------------------------------------------------------------------
// Kernel 3: out = LayerNorm(ctx @ fc_w + q). W AND X staged via DMA.
// ctx is group-swizzled by attn (key = global_row & 7); the DMA source is
// LINEAR over the swizzled array (preserving the swizzle into LDS), and
// ONLY the ds_read XORs the slot — both-sides rule, same as the W path.
// grid (500), block 512 = 8 waves in 2x4; block tile 64 rows x 256 cols.
// ---------------------------------------------------------------------------
__global__ __launch_bounds__(512) void final_kernel(
    const u16* __restrict__ ctx, const u16* __restrict__ fcwT,
    const float* __restrict__ qres, const float* __restrict__ g,
    const float* __restrict__ bta, float* __restrict__ out)
{
    __shared__ __align__(16) u16 Xs[4096];     // [64][64] linear (DMA dest)
    __shared__ __align__(16) u16 Ws[16384];    // [256][64] linear (DMA dest)
    __shared__ float red[4][2][64];   // [wc][s1|s2][row]
    __shared__ float murs[2][64];     // [mu|rs][row]

    const int tid  = threadIdx.x;
    const int wvid = tid >> 6, ln = tid & 63;
    const int n16  = ln & 15, quad = ln >> 4;
    const int wr   = wvid >> 2, wc = wvid & 3;   // 2 x 4
    const int row0 = blockIdx.x * 64;

    f32x4 acc[2][4];
    #pragma unroll
    for (int mt = 0; mt < 2; mt++)
        #pragma unroll
        for (int nt = 0; nt < 4; nt++) acc[mt][nt] = (f32x4){0.f, 0.f, 0.f, 0.f};

    for (int kc = 0; kc < 256; kc += 64) {
        // issue W DMA
        #pragma unroll
        for (int j = 0; j < 4; j++) {
            int idx = tid + 512 * j;
            GLDS16(fcwT + (idx >> 3) * 256 + kc + (idx & 7) * 8, &Ws[idx * 8]);
        }
        // issue X DMA: LINEAR source over pre-swizzled ctx (swizzle lands
        // in LDS; the ds_read below applies the XOR)
        {
            int m = tid >> 3, gg = tid & 7;
            GLDS16(ctx + (size_t)(row0 + m) * 256 + kc + (gg << 3),
                   &Xs[tid * 8]);
        }
        __syncthreads();
        #pragma unroll
        for (int ks = 0; ks < 2; ks++) {
            short8 af[2], bfr[4];
            #pragma unroll
            for (int mt = 0; mt < 2; mt++) {
                int row = wr * 32 + mt * 16 + n16;
                int slot = (ks * 4 + quad) ^ (n16 & 7);   // (row0+row)&7 == n16&7
                af[mt] = *(const short8*)&Xs[row * 64 + slot * 8];
            }
            #pragma unroll
            for (int nt = 0; nt < 4; nt++) {
                int n = wc * 64 + nt * 16 + n16;
                int s = (ks * 4 + quad) ^ (n16 & 7);
                bfr[nt] = *(const short8*)&Ws[n * 64 + s * 8];
            }
            #pragma unroll
            for (int mt = 0; mt < 2; mt++)
                #pragma unroll
                for (int nt = 0; nt < 4; nt++)
                    acc[mt][nt] = __builtin_amdgcn_mfma_f32_16x16x32_bf16(
                        af[mt], bfr[nt], acc[mt][nt], 0, 0, 0);
        }
        __syncthreads();
    }

    // residual add
    #pragma unroll
    for (int mt = 0; mt < 2; mt++) {
        int m0 = row0 + wr * 32 + mt * 16 + quad * 4;
        #pragma unroll
        for (int i = 0; i < 4; i++) {
            const float* rp = &qres[(size_t)(m0 + i) * 256 + wc * 64 + n16];
            #pragma unroll
            for (int nt = 0; nt < 4; nt++)
                acc[mt][nt][i] += rp[nt * 16];
        }
    }
    // per-row partial sums -> LDS
    #pragma unroll
    for (int mt = 0; mt < 2; mt++) {
        #pragma unroll
        for (int i = 0; i < 4; i++) {
            float s1 = 0.f, s2 = 0.f;
            #pragma unroll
            for (int nt = 0; nt < 4; nt++) {
                float vv = acc[mt][nt][i];
                s1 += vv; s2 += vv * vv;
            }
            #pragma unroll
            for (int off = 1; off < 16; off <<= 1) {
                s1 += __shfl_xor(s1, off);
                s2 += __shfl_xor(s2, off);
            }
            if (n16 == 0) {
                int r = wr * 32 + mt * 16 + quad * 4 + i;
                red[wc][0][r] = s1;
                red[wc][1][r] = s2;
            }
        }
    }
    __syncthreads();
    if (tid < 64) {
        float S1 = red[0][0][tid] + red[1][0][tid] + red[2][0][tid] + red[3][0][tid];
        float S2 = red[0][1][tid] + red[1][1][tid] + red[2][1][tid] + red[3][1][tid];
        float mu  = S1 * 0.00390625f;
        float var = S2 * 0.00390625f - mu * mu;
        murs[0][tid] = mu;
        murs[1][tid] = rsqrtf(var + 1e-6f);
    }
    __syncthreads();

    float gv[4], bv[4];
    #pragma unroll
    for (int nt = 0; nt < 4; nt++) {
        int col = wc * 64 + nt * 16 + n16;
        gv[nt] = g[col];
        bv[nt] = bta[col];
    }
    #pragma unroll
    for (int mt = 0; mt < 2; mt++) {
        int rb = wr * 32 + mt * 16 + quad * 4;
        #pragma unroll
        for (int i = 0; i < 4; i++) {
            float mu = murs[0][rb + i];
            float rs = murs[1][rb + i];
            float* op = &out[(size_t)(row0 + rb + i) * 256 + wc * 64 + n16];
            #pragma unroll
            for (int nt = 0; nt < 4; nt++)
                op[nt * 16] = (acc[mt][nt][i] - mu) * rs * gv[nt] + bv[nt];
        }
    }
}

// ---------------------------------------------------------------------------
extern "C" void kernel_launch(void* const* d_in, const int* in_sizes, int n_in,
                              void* d_out, int out_size, void* d_ws, size_t ws_size,
                              hipStream_t stream)
{
    const float* q   = (const float*)d_in[0];
    const float* v   = (const float*)d_in[2];
    const float* wqs = (const float*)d_in[3];
    const float* wvs = (const float*)d_in[4];
    const float* w1  = (const float*)d_in[5];
    const float* b1  = (const float*)d_in[6];
    const float* w2  = (const float*)d_in[7];
    const float* b2  = (const float*)d_in[8];
    const float* fcw = (const float*)d_in[9];
    const float* lng = (const float*)d_in[10];
    const float* lnb = (const float*)d_in[11];
    float* out = (float*)d_out;

    u16* qh_bf = (u16*)d_ws;            // 8,200,192 (padded: attn reads rows <512)
    u16* vhT   = qh_bf + 8200192;       // 8,388,608  (swizzled [bh][4][64][128])
    u16* w1T   = vhT + 8388608;         // 4,096
    u16* w2T   = w1T + 4096;            // 32,768     (group-swizzled [512][64])
    u16* wqT   = w2T + 32768;           // 65,536     (swzW layout)
    u16* wvT   = wqT + 65536;           // 65,536     (swzW layout)
    u16* fcwT  = wvT + 65536;           // 65,536     (swzW layout)
    u16* ctx   = fcwT + 65536;          // 8,192,000  (group-swizzled h-blocks)

    prep_kernel <<<dim3(256),    256, 0, stream>>>(wqs, wvs, fcw, w1, w2,
                                                   wqT, wvT, fcwT, w1T, w2T, vhT);
    proj_kernel <<<dim3(512, 2), 512, 0, stream>>>(q, v, wqT, wvT, qh_bf, vhT);
    attn_kernel <<<dim3(256, 8), 256, 0, stream>>>(qh_bf, vhT, w1T, b1, w2T, b2, ctx);
    final_kernel<<<dim3(500),    512, 0, stream>>>(ctx, fcwT, q, lng, lnb, out);
}